// Round 4
// baseline (1086.114 us; speedup 1.0000x reference)
//
#include <hip/hip_runtime.h>
#include <math.h>

#define NN    768
#define CS    384
#define INF_  100000.0f

typedef __attribute__((ext_vector_type(8))) short s16x8;
typedef __attribute__((ext_vector_type(4))) float f32x4;

// ws offsets in floats
#define OFF_Q       0         // 768*192
#define OFF_K       147456    // 768*192
#define OFF_V       294912    // 768*192
#define OFF_QPRAW   442368    // 768*144
#define OFF_KVPRAW  552960    // 768*432
#define OFF_QPTS    884736    // 768*48*3
#define OFF_KPTS    995328    // 768*48*3
#define OFF_VPTS    1105920   // 768*96*3
#define OFF_KT      1327104   // 192*768 (K transposed [h*16+c][k])
#define OFF_KPT     1474560   // 144*768 (K_pts transposed [h*12+r][k])
#define OFF_BIAS    1585152   // bf16[12][589824] = 3538944 float slots -> ends 5124096
#define OFF_CAT     8414208   // 768*2112

__device__ __forceinline__ unsigned short f2bf(float x) {
  unsigned u = __float_as_uint(x) + 0x8000u;
  return (unsigned short)(u >> 16);
}
__device__ __forceinline__ unsigned pk2(float a, float b) {
  return (unsigned)f2bf(a) | ((unsigned)f2bf(b) << 16);
}
__device__ __forceinline__ float bf2f(unsigned short u) {
  return __uint_as_float(((unsigned)u) << 16);
}

// ---------------------------------------------------------------- K1: projections, tiled GEMM
// C(768x1152) = s(768x384) @ [Wq|Wkv|Wqp|Wkvp]. m-tile 128, n-tile 16, K-chunk 32.
// Thread: 2m x 4n. As[k][m] stride 130 (b64 reads), Bs[k][n] stride 20 (b128 reads).
__global__ void __launch_bounds__(256)
k1_proj(const float* __restrict__ s,
        const float* __restrict__ Wq,  const float* __restrict__ bq,
        const float* __restrict__ Wqp, const float* __restrict__ bqp,
        const float* __restrict__ Wkv, const float* __restrict__ bkv,
        const float* __restrict__ Wkvp,const float* __restrict__ bkvp,
        float* __restrict__ ws) {
  const int n0 = blockIdx.x * 16;   // 72 tiles
  const int m0 = blockIdx.y * 128;  // 6 tiles
  const int t  = threadIdx.x;

  const float* W; const float* bv; int base, ncols;
  if (n0 < 192)      { W = Wq;   bv = bq;   base = 0;   ncols = 192; }
  else if (n0 < 576) { W = Wkv;  bv = bkv;  base = 192; ncols = 384; }
  else if (n0 < 720) { W = Wqp;  bv = bqp;  base = 576; ncols = 144; }
  else               { W = Wkvp; bv = bkvp; base = 720; ncols = 432; }
  const int jj0 = n0 - base;

  __shared__ float As[32 * 130];
  __shared__ float Bs[32 * 20];
  const int tx = t & 3, ty = t >> 2;
  float acc[2][4] = {{0.f}};

  for (int kc = 0; kc < CS; kc += 32) {
    __syncthreads();
    #pragma unroll
    for (int jj = 0; jj < 4; ++jj) {          // A: 128 rows x 32 k
      const int idx = t + 256 * jj;
      const int row = idx >> 3, c4 = idx & 7;
      const float4 v = *(const float4*)&s[(size_t)(m0 + row) * CS + kc + c4 * 4];
      As[(c4 * 4 + 0) * 130 + row] = v.x;
      As[(c4 * 4 + 1) * 130 + row] = v.y;
      As[(c4 * 4 + 2) * 130 + row] = v.z;
      As[(c4 * 4 + 3) * 130 + row] = v.w;
    }
    if (t < 128) {                            // B: 32 k x 16 n
      const int row = t >> 2, c4 = t & 3;
      const float4 v = *(const float4*)&W[(size_t)(kc + row) * ncols + jj0 + c4 * 4];
      *(float4*)&Bs[row * 20 + c4 * 4] = v;
    }
    __syncthreads();
    #pragma unroll 8
    for (int k = 0; k < 32; ++k) {
      const float2 a2 = *(const float2*)&As[k * 130 + ty * 2];
      const float4 b4 = *(const float4*)&Bs[k * 20 + tx * 4];
      acc[0][0] += a2.x * b4.x; acc[0][1] += a2.x * b4.y;
      acc[0][2] += a2.x * b4.z; acc[0][3] += a2.x * b4.w;
      acc[1][0] += a2.y * b4.x; acc[1][1] += a2.y * b4.y;
      acc[1][2] += a2.y * b4.z; acc[1][3] += a2.y * b4.w;
    }
  }

  #pragma unroll
  for (int r = 0; r < 2; ++r) {
    const int n = m0 + ty * 2 + r;
    #pragma unroll
    for (int e = 0; e < 4; ++e) {
      const int j = n0 + tx * 4 + e;
      const float val = acc[r][e] + bv[j - base];
      if (j < 192) {
        (ws + OFF_Q)[n * 192 + j] = val;
      } else if (j < 576) {
        const int jj = j - 192, h = jj >> 5, c = jj & 31;
        if (c < 16) (ws + OFF_K)[n * 192 + h * 16 + c] = val;
        else        (ws + OFF_V)[n * 192 + h * 16 + (c - 16)] = val;
      } else if (j < 720) {
        (ws + OFF_QPRAW)[n * 144 + (j - 576)] = val;
      } else {
        (ws + OFF_KVPRAW)[n * 432 + (j - 720)] = val;
      }
    }
  }
}

// ---------------------------------------------------------------- K2: rotate points (unchanged)
__global__ void __launch_bounds__(256)
k2_rot(const float* __restrict__ rot, const float* __restrict__ trans,
       float* __restrict__ ws) {
  const int idx = blockIdx.x * 256 + threadIdx.x;
  const int n = idx / 192;
  const int r = idx % 192;
  const float* R = rot + n * 9;
  const float* T = trans + n * 3;
  if (r < 48) {
    const float* raw = ws + OFF_QPRAW + n * 144;
    float p0 = raw[r], p1 = raw[48 + r], p2 = raw[96 + r];
    float g0 = R[0]*p0 + R[1]*p1 + R[2]*p2 + T[0];
    float g1 = R[3]*p0 + R[4]*p1 + R[5]*p2 + T[1];
    float g2 = R[6]*p0 + R[7]*p1 + R[8]*p2 + T[2];
    float* qp = ws + OFF_QPTS + n * 144 + r * 3;
    qp[0] = g0; qp[1] = g1; qp[2] = g2;
  } else {
    const int r2 = r - 48;
    const float* raw = ws + OFF_KVPRAW + n * 432;
    float p0 = raw[r2], p1 = raw[144 + r2], p2 = raw[288 + r2];
    float g0 = R[0]*p0 + R[1]*p1 + R[2]*p2 + T[0];
    float g1 = R[3]*p0 + R[4]*p1 + R[5]*p2 + T[1];
    float g2 = R[6]*p0 + R[7]*p1 + R[8]*p2 + T[2];
    const int h = r2 / 12, p = r2 % 12;
    if (p < 4) {
      float* kp = ws + OFF_KPTS + n * 144 + (h * 4 + p) * 3;
      kp[0] = g0; kp[1] = g1; kp[2] = g2;
    } else {
      float* vp = ws + OFF_VPTS + n * 288 + (h * 8 + (p - 4)) * 3;
      vp[0] = g0; vp[1] = g1; vp[2] = g2;
    }
  }
}

// ---------------------------------------------------------------- K2b: transpose K, K_pts to [feat][k]
__global__ void __launch_bounds__(256)
k2b_tr(float* __restrict__ ws) {
  const int i = blockIdx.x * 256 + threadIdx.x;
  if (i < 147456) {
    const int n = i / 192, cc = i % 192;
    (ws + OFF_KT)[cc * 768 + n] = (ws + OFF_K)[i];
  } else {
    const int i2 = i - 147456;
    const int n = i2 / 144, r = i2 % 144;
    (ws + OFF_KPT)[r * 768 + n] = (ws + OFF_KPTS)[i2];
  }
}

// ---------------------------------------------------------------- KB: bias = z @ Wb, streamed, bf16 out [h][q*768+k]
__global__ void __launch_bounds__(256)
kb_bias(const float* __restrict__ z, const float* __restrict__ Wb,
        float* __restrict__ ws) {
  const int row0 = blockIdx.x * 64;   // 9216 blocks over 589824 rows
  const int t = threadIdx.x;
  __shared__ float4 z4[64 * 32];      // phys col = logical ^ (row&31)
  __shared__ float part[4 * 64 * 13];

  const float4* zg = (const float4*)z + (size_t)row0 * 32;
  {
    const int kb = t >> 5, c4 = t & 31;
    #pragma unroll
    for (int j = 0; j < 8; ++j) {
      const int row = kb + 8 * j;
      z4[row * 32 + (c4 ^ (row & 31))] = zg[(size_t)row * 32 + c4];
    }
  }
  __syncthreads();
  {
    const int r = t & 63, cq = t >> 6;   // cq wave-uniform -> Wb via s_loads
    float acc[12];
    #pragma unroll
    for (int h = 0; h < 12; ++h) acc[h] = 0.f;
    #pragma unroll
    for (int i = 0; i < 8; ++i) {
      const int c4l = cq * 8 + i;
      const float4 v = z4[r * 32 + (c4l ^ (r & 31))];
      const float* wb = Wb + c4l * 48;
      #pragma unroll
      for (int h = 0; h < 12; ++h)
        acc[h] += v.x * wb[h] + v.y * wb[12 + h] + v.z * wb[24 + h] + v.w * wb[36 + h];
    }
    #pragma unroll
    for (int h = 0; h < 12; ++h) part[(cq * 64 + r) * 13 + h] = acc[h];
  }
  __syncthreads();
  {
    const int r2 = t & 63, hg = t >> 6;
    unsigned short* bg = (unsigned short*)(ws + OFF_BIAS);
    #pragma unroll
    for (int e = 0; e < 3; ++e) {
      const int h = hg * 3 + e;
      const float v = part[(0 * 64 + r2) * 13 + h] + part[(1 * 64 + r2) * 13 + h]
                    + part[(2 * 64 + r2) * 13 + h] + part[(3 * 64 + r2) * 13 + h];
      bg[(size_t)h * 589824 + row0 + r2] = f2bf(v);
    }
  }
}

// ---------------------------------------------------------------- K3: fused attention (z pass 2)
// One q per block, chunks of 64 k. Only zT staged (bf16, k'=pi(k)=(k&7)*8+(k>>3)).
// bias read from global bf16. o_pair via MFMA, o/o_pt VALU.
#define ZT_S 72
#define WT_S 72
#define WH_S 68
__global__ void __launch_bounds__(256, 6)
k3_fused(const float* __restrict__ z, const float* __restrict__ rot,
         const float* __restrict__ trans, const float* __restrict__ mask,
         const float* __restrict__ bb, const float* __restrict__ hwin,
         float* __restrict__ ws) {
  const int q = blockIdx.x, t = threadIdx.x;
  const int g = t >> 6, kl = t & 63;
  const int l15 = kl & 15, lq = kl >> 4;

  __shared__ unsigned short zT[128 * ZT_S];   // 18432 B
  __shared__ unsigned short wT[16 * WT_S];    // 2304 B
  __shared__ float wH[12 * WH_S];             // 3264 B
  __shared__ float hw_l[12], bb_l[12], lsum[12], linv[12];
  __shared__ float opt_raw[288];

  if (t < 12) {
    hw_l[t] = logf(1.0f + expf(hwin[t])) * 0.13608276348795434f;
    bb_l[t] = bb[t];
  }

  const float maskq = mask[q];
  const float* qrow  = ws + OFF_Q    + q * 192;
  const float* qprow = ws + OFF_QPTS + q * 144;
  const float* ktr   = ws + OFF_KT;
  const float* kptr  = ws + OFF_KPT;
  const float* vbase = ws + OFF_V;
  const float* vpbase= ws + OFF_VPTS;
  const unsigned short* bgr = (const unsigned short*)(ws + OFF_BIAS);
  const float4* zg4  = (const float4*)z + (size_t)q * 24576;

  float l3[3] = {0.f, 0.f, 0.f};
  f32x4 opA = {0.f,0.f,0.f,0.f}, opB = {0.f,0.f,0.f,0.f};
  float o_acc = 0.f, pt0 = 0.f, pt1 = 0.f;
  const int oh = t >> 4;
  const int ph = t / 24;
  const int p2s = 256 + t, p2h = p2s / 24;

  for (int k0 = 0; k0 < NN; k0 += 64) {
    __syncthreads();   // prev phase C done

    // ---- stage zT (two half-chunks, e-rotated writes: conflict-free)
    const int kb = t >> 5, c4 = t & 31;
    #pragma unroll
    for (int half = 0; half < 2; ++half) {
      float4 zv[4];
      #pragma unroll
      for (int j = 0; j < 4; ++j)
        zv[j] = zg4[(size_t)(k0 + kb + 8 * (half * 4 + j)) * 32 + c4];
      #pragma unroll
      for (int w = 0; w < 4; ++w) {
        const int e = ((c4 >> 1) + w) & 3;
        uint2 d;
        d.x = pk2(((const float*)&zv[0])[e], ((const float*)&zv[1])[e]);
        d.y = pk2(((const float*)&zv[2])[e], ((const float*)&zv[3])[e]);
        *(uint2*)&zT[(c4 * 4 + e) * ZT_S + kb * 8 + half * 4] = d;
      }
    }
    __syncthreads();

    // ---- qk/pt/bias -> w (thread owns k = k0+kl, h in {g,g+4,g+8})
    {
      const int kg = k0 + kl;
      const float mterm = INF_ * (maskq * mask[kg] - 1.0f);
      #pragma unroll
      for (int j = 0; j < 3; ++j) {
        const int h = g + 4 * j;
        float qk = 0.f;
        #pragma unroll
        for (int c = 0; c < 16; ++c)
          qk += qrow[h * 16 + c] * ktr[(h * 16 + c) * 768 + kg];
        float pt = 0.f;
        #pragma unroll
        for (int r = 0; r < 12; ++r) {
          const float d = qprow[h * 12 + r] - kptr[(h * 12 + r) * 768 + kg];
          pt += d * d;
        }
        const float bias = bf2f(bgr[(size_t)h * 589824 + (size_t)q * 768 + kg]);
        const float logit = 0.14433756729740643f * qk
                          + 0.57735026918962576f * (bias + bb_l[h])
                          - 0.5f * hw_l[h] * pt + mterm;
        const float wv = __expf(logit);
        l3[j] += wv;
        wH[h * WH_S + kl] = wv;
        wT[h * WT_S + ((kl & 7) * 8 + (kl >> 3))] = f2bf(wv);
      }
    }
    __syncthreads();

    // ---- phase C: o_pair MFMA + o/o_pt VALU
    #pragma unroll
    for (int kk = 0; kk < 2; ++kk) {
      s16x8 af = *(const s16x8*)&wT[l15 * WT_S + kk * 32 + lq * 8];
      s16x8 b0 = *(const s16x8*)&zT[((2 * g)     * 16 + l15) * ZT_S + kk * 32 + lq * 8];
      opA = __builtin_amdgcn_mfma_f32_16x16x32_bf16(af, b0, opA, 0, 0, 0);
      s16x8 b1 = *(const s16x8*)&zT[((2 * g + 1) * 16 + l15) * ZT_S + kk * 32 + lq * 8];
      opB = __builtin_amdgcn_mfma_f32_16x16x32_bf16(af, b1, opB, 0, 0, 0);
    }
    {
      const float* vpr = vpbase + (size_t)k0 * 288;
      const float* vr  = vbase  + (size_t)k0 * 192;
      #pragma unroll 4
      for (int k4 = 0; k4 < 16; ++k4) {
        const int k = k4 * 4;
        {
          const float4 w4 = *(const float4*)&wH[ph * WH_S + k];
          pt0 += w4.x * vpr[(k    ) * 288 + t] + w4.y * vpr[(k + 1) * 288 + t]
               + w4.z * vpr[(k + 2) * 288 + t] + w4.w * vpr[(k + 3) * 288 + t];
        }
        if (t < 32) {
          const float4 w4 = *(const float4*)&wH[p2h * WH_S + k];
          pt1 += w4.x * vpr[(k    ) * 288 + p2s] + w4.y * vpr[(k + 1) * 288 + p2s]
               + w4.z * vpr[(k + 2) * 288 + p2s] + w4.w * vpr[(k + 3) * 288 + p2s];
        }
        if (t < 192) {
          const float4 w4 = *(const float4*)&wH[oh * WH_S + k];
          o_acc += w4.x * vr[(k    ) * 192 + t] + w4.y * vr[(k + 1) * 192 + t]
                 + w4.z * vr[(k + 2) * 192 + t] + w4.w * vr[(k + 3) * 192 + t];
        }
      }
    }
  }

  // ---- l reduction
  #pragma unroll
  for (int j = 0; j < 3; ++j) {
    float v = l3[j];
    for (int off = 1; off < 64; off <<= 1) v += __shfl_xor(v, off, 64);
    l3[j] = v;
  }
  if (kl == 0) { lsum[g] = l3[0]; lsum[g + 4] = l3[1]; lsum[g + 8] = l3[2]; }
  __syncthreads();
  if (t < 12) linv[t] = 1.0f / lsum[t];
  __syncthreads();

  float* cat = ws + OFF_CAT + (size_t)q * 2112;
  #pragma unroll
  for (int r = 0; r < 4; ++r) {
    const int h = lq * 4 + r;
    if (h < 12) {
      cat[576 + h * 128 + (2 * g)     * 16 + l15] = opA[r] * linv[h];
      cat[576 + h * 128 + (2 * g + 1) * 16 + l15] = opB[r] * linv[h];
    }
  }
  if (t < 192) cat[t] = o_acc * linv[oh];
  opt_raw[t] = pt0 * linv[ph];
  if (t < 32) opt_raw[p2s] = pt1 * linv[p2h];
  __syncthreads();

  if (t < 96) {
    const int h = t >> 3, p = t & 7;
    const float* R = rot + q * 9;
    const float* T = trans + q * 3;
    const float g0 = opt_raw[h * 24 + p * 3 + 0] - T[0];
    const float g1 = opt_raw[h * 24 + p * 3 + 1] - T[1];
    const float g2 = opt_raw[h * 24 + p * 3 + 2] - T[2];
    const float x  = R[0]*g0 + R[3]*g1 + R[6]*g2;
    const float y  = R[1]*g0 + R[4]*g1 + R[7]*g2;
    const float zc = R[2]*g0 + R[5]*g1 + R[8]*g2;
    const int hp = h * 8 + p;
    cat[192 + hp] = x;
    cat[288 + hp] = y;
    cat[384 + hp] = zc;
    cat[480 + hp] = sqrtf(x*x + y*y + zc*zc + 1e-8f);
  }
}

// ---------------------------------------------------------------- K5: out GEMM (tiled, K-split 6, atomic)
__global__ void __launch_bounds__(256)
k5_init(const float* __restrict__ bout, float* __restrict__ out) {
  const int i = blockIdx.x * 256 + threadIdx.x;  // 294912
  out[i] = bout[i % 384];
}

__global__ void __launch_bounds__(256)
k5_out(const float* __restrict__ Wout, const float* __restrict__ ws,
       float* __restrict__ out) {
  const int n0  = blockIdx.x * 16;    // 24
  const int m0  = blockIdx.y * 128;   // 6
  const int ks0 = blockIdx.z * 352;   // 6 K-segments
  const int t = threadIdx.x;

  __shared__ float As[32 * 130];
  __shared__ float Bs[32 * 20];
  const int tx = t & 3, ty = t >> 2;
  float acc[2][4] = {{0.f}};

  const float* catg = ws + OFF_CAT;
  for (int kc = 0; kc < 352; kc += 32) {
    __syncthreads();
    #pragma unroll
    for (int jj = 0; jj < 4; ++jj) {
      const int idx = t + 256 * jj;
      const int row = idx >> 3, c4 = idx & 7;
      const float4 v = *(const float4*)&catg[(size_t)(m0 + row) * 2112 + ks0 + kc + c4 * 4];
      As[(c4 * 4 + 0) * 130 + row] = v.x;
      As[(c4 * 4 + 1) * 130 + row] = v.y;
      As[(c4 * 4 + 2) * 130 + row] = v.z;
      As[(c4 * 4 + 3) * 130 + row] = v.w;
    }
    if (t < 128) {
      const int row = t >> 2, c4 = t & 3;
      const float4 v = *(const float4*)&Wout[(size_t)(ks0 + kc + row) * 384 + n0 + c4 * 4];
      *(float4*)&Bs[row * 20 + c4 * 4] = v;
    }
    __syncthreads();
    #pragma unroll 8
    for (int k = 0; k < 32; ++k) {
      const float2 a2 = *(const float2*)&As[k * 130 + ty * 2];
      const float4 b4 = *(const float4*)&Bs[k * 20 + tx * 4];
      acc[0][0] += a2.x * b4.x; acc[0][1] += a2.x * b4.y;
      acc[0][2] += a2.x * b4.z; acc[0][3] += a2.x * b4.w;
      acc[1][0] += a2.y * b4.x; acc[1][1] += a2.y * b4.y;
      acc[1][2] += a2.y * b4.z; acc[1][3] += a2.y * b4.w;
    }
  }
  #pragma unroll
  for (int r = 0; r < 2; ++r)
    #pragma unroll
    for (int e = 0; e < 4; ++e)
      atomicAdd(&out[(size_t)(m0 + ty * 2 + r) * 384 + n0 + tx * 4 + e], acc[r][e]);
}

// ----------------------------------------------------------------
extern "C" void kernel_launch(void* const* d_in, const int* in_sizes, int n_in,
                              void* d_out, int out_size, void* d_ws, size_t ws_size,
                              hipStream_t stream) {
  const float* s     = (const float*)d_in[0];
  const float* z     = (const float*)d_in[1];
  const float* rot   = (const float*)d_in[2];
  const float* trans = (const float*)d_in[3];
  const float* mask  = (const float*)d_in[4];
  const float* Wq    = (const float*)d_in[5];
  const float* bq    = (const float*)d_in[6];
  const float* Wqp   = (const float*)d_in[7];
  const float* bqp   = (const float*)d_in[8];
  const float* Wkv   = (const float*)d_in[9];
  const float* bkv   = (const float*)d_in[10];
  const float* Wkvp  = (const float*)d_in[11];
  const float* bkvp  = (const float*)d_in[12];
  const float* Wb    = (const float*)d_in[13];
  const float* bb    = (const float*)d_in[14];
  const float* hw    = (const float*)d_in[15];
  const float* Wout  = (const float*)d_in[16];
  const float* bout  = (const float*)d_in[17];
  float* out = (float*)d_out;
  float* ws  = (float*)d_ws;

  kb_bias<<<9216, 256, 0, stream>>>(z, Wb, ws);
  k1_proj<<<dim3(72, 6), 256, 0, stream>>>(s, Wq, bq, Wqp, bqp, Wkv, bkv, Wkvp, bkvp, ws);
  k2_rot <<<576, 256, 0, stream>>>(rot, trans, ws);
  k2b_tr <<<1008, 256, 0, stream>>>(ws);
  k3_fused<<<NN, 256, 0, stream>>>(z, rot, trans, mask, bb, hw, ws);
  k5_init<<<1152, 256, 0, stream>>>(bout, out);
  k5_out<<<dim3(24, 6, 6), 256, 0, stream>>>(Wout, ws, out);
}

// Round 5
// 738.487 us; speedup vs baseline: 1.4707x; 1.4707x over previous
//
#include <hip/hip_runtime.h>
#include <math.h>

#define NN    768
#define CS    384
#define INF_  100000.0f

typedef __attribute__((ext_vector_type(8))) short s16x8;
typedef __attribute__((ext_vector_type(4))) float f32x4;

// ws offsets in floats
#define OFF_Q       0         // 768*192
#define OFF_K       147456    // 768*192
#define OFF_V       294912    // 768*192
#define OFF_QPRAW   442368    // 768*144
#define OFF_KVPRAW  552960    // 768*432
#define OFF_QPTS    884736    // 768*48*3
#define OFF_KPTS    995328    // 768*48*3
#define OFF_VPTS    1105920   // 768*96*3
#define OFF_KT      1327104   // 192*768 (K transposed [h*16+c][k])
#define OFF_KPT     1474560   // 144*768 (K_pts transposed [h*12+r][k])
#define OFF_S       1585152   // bf16 S[q][h][k] = 7077888 bf16 = 3538944 floats -> ends 5124096
#define OFF_CAT     8414208   // 768*2112

__device__ __forceinline__ unsigned short f2bf(float x) {
  unsigned u = __float_as_uint(x) + 0x8000u;
  return (unsigned short)(u >> 16);
}
__device__ __forceinline__ unsigned pk2(float a, float b) {
  return (unsigned)f2bf(a) | ((unsigned)f2bf(b) << 16);
}
__device__ __forceinline__ float bf2f(unsigned short u) {
  return __uint_as_float(((unsigned)u) << 16);
}

// ---------------------------------------------------------------- K1: projections, tiled GEMM (unchanged)
__global__ void __launch_bounds__(256)
k1_proj(const float* __restrict__ s,
        const float* __restrict__ Wq,  const float* __restrict__ bq,
        const float* __restrict__ Wqp, const float* __restrict__ bqp,
        const float* __restrict__ Wkv, const float* __restrict__ bkv,
        const float* __restrict__ Wkvp,const float* __restrict__ bkvp,
        float* __restrict__ ws) {
  const int n0 = blockIdx.x * 16;
  const int m0 = blockIdx.y * 128;
  const int t  = threadIdx.x;

  const float* W; const float* bv; int base, ncols;
  if (n0 < 192)      { W = Wq;   bv = bq;   base = 0;   ncols = 192; }
  else if (n0 < 576) { W = Wkv;  bv = bkv;  base = 192; ncols = 384; }
  else if (n0 < 720) { W = Wqp;  bv = bqp;  base = 576; ncols = 144; }
  else               { W = Wkvp; bv = bkvp; base = 720; ncols = 432; }
  const int jj0 = n0 - base;

  __shared__ float As[32 * 130];
  __shared__ float Bs[32 * 20];
  const int tx = t & 3, ty = t >> 2;
  float acc[2][4] = {{0.f}};

  for (int kc = 0; kc < CS; kc += 32) {
    __syncthreads();
    #pragma unroll
    for (int jj = 0; jj < 4; ++jj) {
      const int idx = t + 256 * jj;
      const int row = idx >> 3, c4 = idx & 7;
      const float4 v = *(const float4*)&s[(size_t)(m0 + row) * CS + kc + c4 * 4];
      As[(c4 * 4 + 0) * 130 + row] = v.x;
      As[(c4 * 4 + 1) * 130 + row] = v.y;
      As[(c4 * 4 + 2) * 130 + row] = v.z;
      As[(c4 * 4 + 3) * 130 + row] = v.w;
    }
    if (t < 128) {
      const int row = t >> 2, c4 = t & 3;
      const float4 v = *(const float4*)&W[(size_t)(kc + row) * ncols + jj0 + c4 * 4];
      *(float4*)&Bs[row * 20 + c4 * 4] = v;
    }
    __syncthreads();
    #pragma unroll 8
    for (int k = 0; k < 32; ++k) {
      const float2 a2 = *(const float2*)&As[k * 130 + ty * 2];
      const float4 b4 = *(const float4*)&Bs[k * 20 + tx * 4];
      acc[0][0] += a2.x * b4.x; acc[0][1] += a2.x * b4.y;
      acc[0][2] += a2.x * b4.z; acc[0][3] += a2.x * b4.w;
      acc[1][0] += a2.y * b4.x; acc[1][1] += a2.y * b4.y;
      acc[1][2] += a2.y * b4.z; acc[1][3] += a2.y * b4.w;
    }
  }

  #pragma unroll
  for (int r = 0; r < 2; ++r) {
    const int n = m0 + ty * 2 + r;
    #pragma unroll
    for (int e = 0; e < 4; ++e) {
      const int j = n0 + tx * 4 + e;
      const float val = acc[r][e] + bv[j - base];
      if (j < 192) {
        (ws + OFF_Q)[n * 192 + j] = val;
      } else if (j < 576) {
        const int jj = j - 192, h = jj >> 5, c = jj & 31;
        if (c < 16) (ws + OFF_K)[n * 192 + h * 16 + c] = val;
        else        (ws + OFF_V)[n * 192 + h * 16 + (c - 16)] = val;
      } else if (j < 720) {
        (ws + OFF_QPRAW)[n * 144 + (j - 576)] = val;
      } else {
        (ws + OFF_KVPRAW)[n * 432 + (j - 720)] = val;
      }
    }
  }
}

// ---------------------------------------------------------------- K2: rotate points (unchanged)
__global__ void __launch_bounds__(256)
k2_rot(const float* __restrict__ rot, const float* __restrict__ trans,
       float* __restrict__ ws) {
  const int idx = blockIdx.x * 256 + threadIdx.x;
  const int n = idx / 192;
  const int r = idx % 192;
  const float* R = rot + n * 9;
  const float* T = trans + n * 3;
  if (r < 48) {
    const float* raw = ws + OFF_QPRAW + n * 144;
    float p0 = raw[r], p1 = raw[48 + r], p2 = raw[96 + r];
    float g0 = R[0]*p0 + R[1]*p1 + R[2]*p2 + T[0];
    float g1 = R[3]*p0 + R[4]*p1 + R[5]*p2 + T[1];
    float g2 = R[6]*p0 + R[7]*p1 + R[8]*p2 + T[2];
    float* qp = ws + OFF_QPTS + n * 144 + r * 3;
    qp[0] = g0; qp[1] = g1; qp[2] = g2;
  } else {
    const int r2 = r - 48;
    const float* raw = ws + OFF_KVPRAW + n * 432;
    float p0 = raw[r2], p1 = raw[144 + r2], p2 = raw[288 + r2];
    float g0 = R[0]*p0 + R[1]*p1 + R[2]*p2 + T[0];
    float g1 = R[3]*p0 + R[4]*p1 + R[5]*p2 + T[1];
    float g2 = R[6]*p0 + R[7]*p1 + R[8]*p2 + T[2];
    const int h = r2 / 12, p = r2 % 12;
    if (p < 4) {
      float* kp = ws + OFF_KPTS + n * 144 + (h * 4 + p) * 3;
      kp[0] = g0; kp[1] = g1; kp[2] = g2;
    } else {
      float* vp = ws + OFF_VPTS + n * 288 + (h * 8 + (p - 4)) * 3;
      vp[0] = g0; vp[1] = g1; vp[2] = g2;
    }
  }
}

// ---------------------------------------------------------------- K2b: transpose K, K_pts to [feat][k] (unchanged)
__global__ void __launch_bounds__(256)
k2b_tr(float* __restrict__ ws) {
  const int i = blockIdx.x * 256 + threadIdx.x;
  if (i < 147456) {
    const int n = i / 192, cc = i % 192;
    (ws + OFF_KT)[cc * 768 + n] = (ws + OFF_K)[i];
  } else {
    const int i2 = i - 147456;
    const int n = i2 / 144, r = i2 % 144;
    (ws + OFF_KPT)[r * 768 + n] = (ws + OFF_KPTS)[i2];
  }
}

// ---------------------------------------------------------------- KS: S[q][h][k] = c1*qk - 0.5*hw*pt + c2*bb + mask  (bf16)
// Grid: x = k-chunk (12), y = q-tile (48). Wave g handles h in {g,g+4,g+8};
// thread kl owns k = k0+kl. F (K,KP features) in regs from coalesced transposed
// reads; Q/QP via wave-uniform s_loads in the q-loop.
__global__ void __launch_bounds__(256)
ks_scores(const float* __restrict__ mask, const float* __restrict__ bb,
          const float* __restrict__ hwin, float* __restrict__ ws) {
  const int k0 = blockIdx.x * 64;
  const int q0 = blockIdx.y * 16;
  const int t = threadIdx.x;
  const int g = t >> 6, kl = t & 63;
  const int kg = k0 + kl;

  const float* ktr  = ws + OFF_KT;
  const float* kptr = ws + OFF_KPT;
  float F[3][28];
  #pragma unroll
  for (int j = 0; j < 3; ++j) {
    const int h = g + 4 * j;
    #pragma unroll
    for (int c = 0; c < 16; ++c) F[j][c] = ktr[(h * 16 + c) * 768 + kg];
    #pragma unroll
    for (int r = 0; r < 12; ++r) F[j][16 + r] = kptr[(h * 12 + r) * 768 + kg];
  }
  float hw3[3], bb3[3];
  #pragma unroll
  for (int j = 0; j < 3; ++j) {
    const int h = g + 4 * j;
    hw3[j] = logf(1.0f + expf(hwin[h])) * 0.13608276348795434f;  // softplus*sqrt(1/54)
    bb3[j] = 0.57735026918962576f * bb[h];
  }
  const float maskk = mask[kg];
  unsigned short* Sg = (unsigned short*)(ws + OFF_S);

  for (int qi = 0; qi < 16; ++qi) {
    const int q = q0 + qi;
    const float mterm = INF_ * (mask[q] * maskk - 1.0f);
    const float* qrow  = ws + OFF_Q    + q * 192;   // uniform -> s_loads
    const float* qprow = ws + OFF_QPTS + q * 144;
    #pragma unroll
    for (int j = 0; j < 3; ++j) {
      const int h = g + 4 * j;
      float qk = 0.f;
      #pragma unroll
      for (int c = 0; c < 16; ++c) qk += qrow[h * 16 + c] * F[j][c];
      float pt = 0.f;
      #pragma unroll
      for (int r = 0; r < 12; ++r) {
        const float d = qprow[h * 12 + r] - F[j][16 + r];
        pt += d * d;
      }
      const float S = 0.14433756729740643f * qk - 0.5f * hw3[j] * pt
                    + bb3[j] + mterm;
      Sg[(size_t)(q * 12 + h) * 768 + kg] = f2bf(S);
    }
  }
}

// ---------------------------------------------------------------- K3: fused single-z-pass attention
// One q per block, chunks of 64 k. z staged bf16 in zR (row-major, bias MFMA
// B-frags) and zT (transposed, pi(k), o_pair B-frags). bias via MFMA with
// resident Wb A-frags (R3-proven). S read coalesced bf16. o/o_pt VALU from
// L2-resident V/VPTS. Normalize at end (logits bounded, no max-subtraction).
#define ZT_S 72
#define ZR_S 136
#define WT_S 72
#define WH_S 68
__global__ void __launch_bounds__(256, 3)
k3_fused(const float* __restrict__ z, const float* __restrict__ rot,
         const float* __restrict__ trans, const float* __restrict__ Wb,
         float* __restrict__ ws) {
  const int q = blockIdx.x, t = threadIdx.x;
  const int g = t >> 6, kl = t & 63;
  const int l15 = kl & 15, lq = kl >> 4;

  __shared__ unsigned short zT[128 * ZT_S];   // 18432 B
  __shared__ unsigned short zR[64 * ZR_S];    // 17408 B
  __shared__ unsigned short wT[16 * WT_S];    // 2304 B
  __shared__ float wH[12 * WH_S];             // 3264 B
  __shared__ float bias_s[64 * 13];           // 3328 B
  __shared__ float lsum[12], linv[12];
  __shared__ float opt_raw[288];

  // resident bias A-frags: A[m=h][c] = Wb[c][h] (rows 12..15 zero)
  s16x8 wbA[4];
  #pragma unroll
  for (int kk = 0; kk < 4; ++kk) {
    #pragma unroll
    for (int j = 0; j < 8; ++j) {
      float v = (l15 < 12) ? Wb[(kk * 32 + lq * 8 + j) * 12 + l15] : 0.0f;
      wbA[kk][j] = (short)f2bf(v);
    }
  }

  const float* vbase = ws + OFF_V;
  const float* vpbase= ws + OFF_VPTS;
  const unsigned short* Sg = (const unsigned short*)(ws + OFF_S);
  const float4* zg4  = (const float4*)z + (size_t)q * 24576;

  float l3[3] = {0.f, 0.f, 0.f};
  f32x4 opA = {0.f,0.f,0.f,0.f}, opB = {0.f,0.f,0.f,0.f};
  float o_acc = 0.f, pt0 = 0.f, pt1 = 0.f;
  const int oh = t >> 4;
  const int ph = t / 24;
  const int p2s = 256 + t, p2h = p2s / 24;

  for (int k0 = 0; k0 < NN; k0 += 64) {
    __syncthreads();   // prev phase C done

    // ---- stage zR + zT (two half-chunks; zT e-rotated, pi(k)=(k&7)*8+(k>>3))
    const int kb = t >> 5, c4 = t & 31;
    #pragma unroll
    for (int half = 0; half < 2; ++half) {
      float4 zv[4];
      #pragma unroll
      for (int j = 0; j < 4; ++j)
        zv[j] = zg4[(size_t)(k0 + kb + 8 * (half * 4 + j)) * 32 + c4];
      #pragma unroll
      for (int j = 0; j < 4; ++j) {
        uint2 d;
        d.x = pk2(zv[j].x, zv[j].y);
        d.y = pk2(zv[j].z, zv[j].w);
        *(uint2*)&zR[(kb + 8 * (half * 4 + j)) * ZR_S + c4 * 4] = d;
      }
      #pragma unroll
      for (int w = 0; w < 4; ++w) {
        const int e = ((c4 >> 1) + w) & 3;
        uint2 d;
        d.x = pk2(((const float*)&zv[0])[e], ((const float*)&zv[1])[e]);
        d.y = pk2(((const float*)&zv[2])[e], ((const float*)&zv[3])[e]);
        *(uint2*)&zT[(c4 * 4 + e) * ZT_S + kb * 8 + half * 4] = d;
      }
    }
    __syncthreads();

    // ---- bias MFMA: wave g -> k-tile g; D row = h, col = k-in-tile
    {
      f32x4 bd = {0.f,0.f,0.f,0.f};
      #pragma unroll
      for (int kk = 0; kk < 4; ++kk) {
        s16x8 bf = *(const s16x8*)&zR[(g * 16 + l15) * ZR_S + kk * 32 + lq * 8];
        bd = __builtin_amdgcn_mfma_f32_16x16x32_bf16(wbA[kk], bf, bd, 0, 0, 0);
      }
      #pragma unroll
      for (int r = 0; r < 4; ++r) {
        const int h = lq * 4 + r;
        if (h < 12) bias_s[(g * 16 + l15) * 13 + h] = bd[r];
      }
    }
    __syncthreads();

    // ---- w = exp(S + c2*bias); store wT (bf16, pi-order) + wH (f32)
    {
      const int kg = k0 + kl;
      #pragma unroll
      for (int j = 0; j < 3; ++j) {
        const int h = g + 4 * j;
        const float Sv = bf2f(Sg[(size_t)(q * 12 + h) * 768 + kg]);
        const float wv = __expf(Sv + 0.57735026918962576f * bias_s[kl * 13 + h]);
        l3[j] += wv;
        wH[h * WH_S + kl] = wv;
        wT[h * WT_S + ((kl & 7) * 8 + (kl >> 3))] = f2bf(wv);
      }
    }
    __syncthreads();

    // ---- phase C: o_pair MFMA + o/o_pt VALU
    #pragma unroll
    for (int kk = 0; kk < 2; ++kk) {
      s16x8 af = *(const s16x8*)&wT[l15 * WT_S + kk * 32 + lq * 8];
      s16x8 b0 = *(const s16x8*)&zT[((2 * g)     * 16 + l15) * ZT_S + kk * 32 + lq * 8];
      opA = __builtin_amdgcn_mfma_f32_16x16x32_bf16(af, b0, opA, 0, 0, 0);
      s16x8 b1 = *(const s16x8*)&zT[((2 * g + 1) * 16 + l15) * ZT_S + kk * 32 + lq * 8];
      opB = __builtin_amdgcn_mfma_f32_16x16x32_bf16(af, b1, opB, 0, 0, 0);
    }
    {
      const float* vpr = vpbase + (size_t)k0 * 288;
      const float* vr  = vbase  + (size_t)k0 * 192;
      #pragma unroll 4
      for (int k4 = 0; k4 < 16; ++k4) {
        const int k = k4 * 4;
        {
          const float4 w4 = *(const float4*)&wH[ph * WH_S + k];
          pt0 += w4.x * vpr[(k    ) * 288 + t] + w4.y * vpr[(k + 1) * 288 + t]
               + w4.z * vpr[(k + 2) * 288 + t] + w4.w * vpr[(k + 3) * 288 + t];
        }
        if (t < 32) {
          const float4 w4 = *(const float4*)&wH[p2h * WH_S + k];
          pt1 += w4.x * vpr[(k    ) * 288 + p2s] + w4.y * vpr[(k + 1) * 288 + p2s]
               + w4.z * vpr[(k + 2) * 288 + p2s] + w4.w * vpr[(k + 3) * 288 + p2s];
        }
        if (t < 192) {
          const float4 w4 = *(const float4*)&wH[oh * WH_S + k];
          o_acc += w4.x * vr[(k    ) * 192 + t] + w4.y * vr[(k + 1) * 192 + t]
                 + w4.z * vr[(k + 2) * 192 + t] + w4.w * vr[(k + 3) * 192 + t];
        }
      }
    }
  }

  // ---- l reduction
  #pragma unroll
  for (int j = 0; j < 3; ++j) {
    float v = l3[j];
    for (int off = 1; off < 64; off <<= 1) v += __shfl_xor(v, off, 64);
    l3[j] = v;
  }
  if (kl == 0) { lsum[g] = l3[0]; lsum[g + 4] = l3[1]; lsum[g + 8] = l3[2]; }
  __syncthreads();
  if (t < 12) linv[t] = 1.0f / lsum[t];
  __syncthreads();

  float* cat = ws + OFF_CAT + (size_t)q * 2112;
  #pragma unroll
  for (int r = 0; r < 4; ++r) {
    const int h = lq * 4 + r;
    if (h < 12) {
      cat[576 + h * 128 + (2 * g)     * 16 + l15] = opA[r] * linv[h];
      cat[576 + h * 128 + (2 * g + 1) * 16 + l15] = opB[r] * linv[h];
    }
  }
  if (t < 192) cat[t] = o_acc * linv[oh];
  opt_raw[t] = pt0 * linv[ph];
  if (t < 32) opt_raw[p2s] = pt1 * linv[p2h];
  __syncthreads();

  if (t < 96) {
    const int h = t >> 3, p = t & 7;
    const float* R = rot + q * 9;
    const float* T = trans + q * 3;
    const float g0 = opt_raw[h * 24 + p * 3 + 0] - T[0];
    const float g1 = opt_raw[h * 24 + p * 3 + 1] - T[1];
    const float g2 = opt_raw[h * 24 + p * 3 + 2] - T[2];
    const float x  = R[0]*g0 + R[3]*g1 + R[6]*g2;
    const float y  = R[1]*g0 + R[4]*g1 + R[7]*g2;
    const float zc = R[2]*g0 + R[5]*g1 + R[8]*g2;
    const int hp = h * 8 + p;
    cat[192 + hp] = x;
    cat[288 + hp] = y;
    cat[384 + hp] = zc;
    cat[480 + hp] = sqrtf(x*x + y*y + zc*zc + 1e-8f);
  }
}

// ---------------------------------------------------------------- K5: out GEMM 64m x 64n, K-split 6, atomic
__global__ void __launch_bounds__(256)
k5_init(const float* __restrict__ bout, float* __restrict__ out) {
  const int i = blockIdx.x * 256 + threadIdx.x;  // 294912
  out[i] = bout[i % 384];
}

__global__ void __launch_bounds__(256)
k5_out(const float* __restrict__ Wout, const float* __restrict__ ws,
       float* __restrict__ out) {
  const int n0  = blockIdx.x * 64;    // 6
  const int m0  = blockIdx.y * 64;    // 12
  const int ks0 = blockIdx.z * 352;   // 6
  const int t = threadIdx.x;

  __shared__ float As[32 * 68];   // [k][m]
  __shared__ float Bs[32 * 68];   // [k][n]
  const int tx = t & 15, ty = t >> 4;
  float acc[4][4] = {{0.f}};

  const float* catg = ws + OFF_CAT;
  for (int kc = 0; kc < 352; kc += 32) {
    __syncthreads();
    #pragma unroll
    for (int p = 0; p < 2; ++p) {            // A: 64 m x 32 k (float4 read, scatter write)
      const int idx = t + 256 * p;
      const int m = idx >> 3, c4 = idx & 7;
      const float4 v = *(const float4*)&catg[(size_t)(m0 + m) * 2112 + ks0 + kc + c4 * 4];
      As[(c4 * 4 + 0) * 68 + m] = v.x;
      As[(c4 * 4 + 1) * 68 + m] = v.y;
      As[(c4 * 4 + 2) * 68 + m] = v.z;
      As[(c4 * 4 + 3) * 68 + m] = v.w;
    }
    #pragma unroll
    for (int p = 0; p < 8; ++p) {            // B: 32 k x 64 n (coalesced)
      const int idx = t + 256 * p;
      const int k = idx >> 6, n = idx & 63;
      Bs[k * 68 + n] = Wout[(size_t)(ks0 + kc + k) * 384 + n0 + n];
    }
    __syncthreads();
    #pragma unroll 8
    for (int k = 0; k < 32; ++k) {
      const float4 a4 = *(const float4*)&As[k * 68 + ty * 4];
      const float4 b4 = *(const float4*)&Bs[k * 68 + tx * 4];
      acc[0][0] += a4.x * b4.x; acc[0][1] += a4.x * b4.y; acc[0][2] += a4.x * b4.z; acc[0][3] += a4.x * b4.w;
      acc[1][0] += a4.y * b4.x; acc[1][1] += a4.y * b4.y; acc[1][2] += a4.y * b4.z; acc[1][3] += a4.y * b4.w;
      acc[2][0] += a4.z * b4.x; acc[2][1] += a4.z * b4.y; acc[2][2] += a4.z * b4.z; acc[2][3] += a4.z * b4.w;
      acc[3][0] += a4.w * b4.x; acc[3][1] += a4.w * b4.y; acc[3][2] += a4.w * b4.z; acc[3][3] += a4.w * b4.w;
    }
  }
  #pragma unroll
  for (int r = 0; r < 4; ++r)
    #pragma unroll
    for (int c = 0; c < 4; ++c)
      atomicAdd(&out[(size_t)(m0 + ty * 4 + r) * 384 + n0 + tx * 4 + c], acc[r][c]);
}

// ----------------------------------------------------------------
extern "C" void kernel_launch(void* const* d_in, const int* in_sizes, int n_in,
                              void* d_out, int out_size, void* d_ws, size_t ws_size,
                              hipStream_t stream) {
  const float* s     = (const float*)d_in[0];
  const float* z     = (const float*)d_in[1];
  const float* rot   = (const float*)d_in[2];
  const float* trans = (const float*)d_in[3];
  const float* mask  = (const float*)d_in[4];
  const float* Wq    = (const float*)d_in[5];
  const float* bq    = (const float*)d_in[6];
  const float* Wqp   = (const float*)d_in[7];
  const float* bqp   = (const float*)d_in[8];
  const float* Wkv   = (const float*)d_in[9];
  const float* bkv   = (const float*)d_in[10];
  const float* Wkvp  = (const float*)d_in[11];
  const float* bkvp  = (const float*)d_in[12];
  const float* Wb    = (const float*)d_in[13];
  const float* bb    = (const float*)d_in[14];
  const float* hw    = (const float*)d_in[15];
  const float* Wout  = (const float*)d_in[16];
  const float* bout  = (const float*)d_in[17];
  float* out = (float*)d_out;
  float* ws  = (float*)d_ws;

  k1_proj<<<dim3(72, 6), 256, 0, stream>>>(s, Wq, bq, Wqp, bqp, Wkv, bkv, Wkvp, bkvp, ws);
  k2_rot <<<576, 256, 0, stream>>>(rot, trans, ws);
  k2b_tr <<<1008, 256, 0, stream>>>(ws);
  ks_scores<<<dim3(12, 48), 256, 0, stream>>>(mask, bb, hw, ws);
  k3_fused<<<NN, 256, 0, stream>>>(z, rot, trans, Wb, ws);
  k5_init<<<1152, 256, 0, stream>>>(bout, out);
  k5_out<<<dim3(6, 12, 6), 256, 0, stream>>>(Wout, ws, out);
}